// Round 11
// baseline (191.620 us; speedup 1.0000x reference)
//
#include <hip/hip_runtime.h>

#define DIM 128
#define LEN 256
#define INV_SQRT_D 0.08838834764831845f
#define LOG2E 1.4426950408889634f
#define SCALE_L2 (INV_SQRT_D * LOG2E)

__device__ __forceinline__ float bl(unsigned u) { return __uint_as_float(u << 16); }
__device__ __forceinline__ float bh(unsigned u) { return __uint_as_float(u & 0xffff0000u); }

struct AttnSmem {
    float2 ibw[LEN];      // .x = idx bits, .y = mask bias (log2 units)
    float  OW[4][DIM];
    float  Zw[4];
};

// ---------------- f32 attention core (fallback tiers) ----------------
__device__ __forceinline__ void attn_core_f32(
    AttnSmem& sm, int t, int b,
    const float4& va, const float4& vb, float qterm,
    const float* __restrict__ sub_feat, float* __restrict__ out)
{
    const int lane = t & 63;
    const int wv   = t >> 6;
    const int g    = lane >> 4;
    const int m16  = lane & 15;

    float Zr = 0.f;
    float O0=0.f,O1=0.f,O2=0.f,O3=0.f,O4=0.f,O5=0.f,O6=0.f,O7=0.f;

    const int jbase = wv * 64;
    #pragma unroll 4
    for (int k = 0; k < 16; ++k) {
        const float2 ibp = sm.ibw[jbase + 4 * k + g];
        const int   ij = __float_as_int(ibp.x);
        const float bj = ibp.y;
        const float* rp = sub_feat + (size_t)ij * DIM + 8 * m16;
        const float4 u0 = *reinterpret_cast<const float4*>(rp);
        const float4 u1 = *reinterpret_cast<const float4*>(rp + 4);
        const float f0 = u0.x, f1 = u0.y, f2 = u0.z, f3 = u0.w;
        const float f4 = u1.x, f5 = u1.y, f6 = u1.z, f7 = u1.w;
        float sd = f0*va.x + f1*va.y + f2*va.z + f3*va.w
                 + f4*vb.x + f5*vb.y + f6*vb.z + f7*vb.w;
        sd += __shfl_xor(sd, 1);
        sd += __shfl_xor(sd, 2);
        sd += __shfl_xor(sd, 4);
        sd += __shfl_xor(sd, 8);
        const float e = exp2f(sd + qterm + bj);
        Zr += e;
        O0 = fmaf(e, f0, O0); O1 = fmaf(e, f1, O1);
        O2 = fmaf(e, f2, O2); O3 = fmaf(e, f3, O3);
        O4 = fmaf(e, f4, O4); O5 = fmaf(e, f5, O5);
        O6 = fmaf(e, f6, O6); O7 = fmaf(e, f7, O7);
    }

    #pragma unroll
    for (int msk = 16; msk <= 32; msk <<= 1) {
        Zr += __shfl_xor(Zr, msk);
        O0 += __shfl_xor(O0, msk); O1 += __shfl_xor(O1, msk);
        O2 += __shfl_xor(O2, msk); O3 += __shfl_xor(O3, msk);
        O4 += __shfl_xor(O4, msk); O5 += __shfl_xor(O5, msk);
        O6 += __shfl_xor(O6, msk); O7 += __shfl_xor(O7, msk);
    }
    if (lane < 16) {
        reinterpret_cast<float4*>(&sm.OW[wv][0])[2 * m16]     = make_float4(O0, O1, O2, O3);
        reinterpret_cast<float4*>(&sm.OW[wv][0])[2 * m16 + 1] = make_float4(O4, O5, O6, O7);
    }
    if (lane == 0) sm.Zw[wv] = Zr;
    __syncthreads();

    if (t < DIM) {
        const float Zt = sm.Zw[0] + sm.Zw[1] + sm.Zw[2] + sm.Zw[3];
        out[(size_t)b * DIM + t] =
            (sm.OW[0][t] + sm.OW[1][t] + sm.OW[2][t] + sm.OW[3][t]) / Zt;
    }
}

// ---------------- D1: vq (8 batches/block, no Mt) + bf16 convert ----------------
__global__ __launch_bounds__(256) void prep2_kernel(
    const float* __restrict__ sub_feat, const int* __restrict__ sub_index,
    const float* __restrict__ Wq, const float* __restrict__ bq,
    const float* __restrict__ Wk, const float* __restrict__ bk,
    float* __restrict__ vout, float* __restrict__ qout,
    ushort* __restrict__ bfb, int n4, int B, int nv)
{
    const int t   = threadIdx.x;
    const int bid = blockIdx.x;

    if (bid >= nv) {
        // bf16 convert (RNE)
        const int i = (bid - nv) * 256 + t;
        if (i < n4) {
            const float4 u = reinterpret_cast<const float4*>(sub_feat)[i];
            ushort4 o;
            unsigned a;
            a = __float_as_uint(u.x); o.x = (ushort)((a + 0x7fffu + ((a >> 16) & 1u)) >> 16);
            a = __float_as_uint(u.y); o.y = (ushort)((a + 0x7fffu + ((a >> 16) & 1u)) >> 16);
            a = __float_as_uint(u.z); o.z = (ushort)((a + 0x7fffu + ((a >> 16) & 1u)) >> 16);
            a = __float_as_uint(u.w); o.w = (ushort)((a + 0x7fffu + ((a >> 16) & 1u)) >> 16);
            reinterpret_cast<ushort4*>(bfb)[i] = o;
        }
        return;
    }

    const int lane = t & 63;
    const int wv   = t >> 6;
    const int b0   = bid * 8;

    __shared__ float g0[8][DIM];
    __shared__ float ph[2][8][DIM];
    __shared__ float q0[8][DIM];

    #pragma unroll
    for (int s = 0; s < 2; ++s) {
        const int bb = wv * 2 + s;
        const int b  = b0 + bb;
        if (b < B) {
            const int r0 = sub_index[(size_t)b * LEN];
            const float2 p = reinterpret_cast<const float2*>(sub_feat + (size_t)r0 * DIM)[lane];
            g0[bb][2 * lane]     = p.x;
            g0[bb][2 * lane + 1] = p.y;
        } else {
            g0[bb][2 * lane] = 0.f; g0[bb][2 * lane + 1] = 0.f;
        }
    }
    __syncthreads();

    const int d = t & (DIM - 1);
    const int h = t >> 7;

    // q0[b][d] = sum_e g0[b][e] * Wq[e][d] + bq[d]
    {
        float acc[8] = {0.f,0.f,0.f,0.f,0.f,0.f,0.f,0.f};
        const int e0 = h * 64;
        #pragma unroll 4
        for (int e = e0; e < e0 + 64; ++e) {
            const float w = Wq[e * DIM + d];
            #pragma unroll
            for (int bb = 0; bb < 8; ++bb) acc[bb] = fmaf(g0[bb][e], w, acc[bb]);
        }
        #pragma unroll
        for (int bb = 0; bb < 8; ++bb) ph[h][bb][d] = acc[bb];
    }
    __syncthreads();
    if (h == 0) {
        #pragma unroll
        for (int bb = 0; bb < 8; ++bb) q0[bb][d] = ph[0][bb][d] + ph[1][bb][d] + bq[d];
    }
    __syncthreads();

    // q0bk[b] pre-scaled
    #pragma unroll
    for (int s = 0; s < 2; ++s) {
        const int bb = wv * 2 + s;
        float p = q0[bb][lane] * bk[lane] + q0[bb][lane + 64] * bk[lane + 64];
        #pragma unroll
        for (int o = 32; o > 0; o >>= 1) p += __shfl_xor(p, o);
        if (lane == 0 && b0 + bb < B) qout[b0 + bb] = p * SCALE_L2;
    }

    // v[b][i] = Wk[i,:] . q0[b]
    {
        float acc[8] = {0.f,0.f,0.f,0.f,0.f,0.f,0.f,0.f};
        const int d0 = h * 64;
        const float* wrow = Wk + (size_t)d * DIM + d0;
        #pragma unroll 4
        for (int dd = 0; dd < 64; ++dd) {
            const float w = wrow[dd];
            #pragma unroll
            for (int bb = 0; bb < 8; ++bb) acc[bb] = fmaf(w, q0[bb][d0 + dd], acc[bb]);
        }
        #pragma unroll
        for (int bb = 0; bb < 8; ++bb) ph[h][bb][d] = acc[bb];
    }
    __syncthreads();
    if (h == 0) {
        #pragma unroll
        for (int bb = 0; bb < 8; ++bb) {
            if (b0 + bb < B)
                vout[(size_t)(b0 + bb) * DIM + d] = (ph[0][bb][d] + ph[1][bb][d]) * SCALE_L2;
        }
    }
}

// ---------------- D2: attention, depth-4 pipeline, 8 blocks/CU, no spills ----------------
__global__ __launch_bounds__(256, 8) void attn_bf16_kernel(
    const ushort* __restrict__ gfeat, const float* __restrict__ mask,
    const int* __restrict__ sub_index, const float* __restrict__ vbuf,
    const float* __restrict__ qbuf, float* __restrict__ out)
{
    const int t    = threadIdx.x;
    const int lane = t & 63;
    const int wv   = t >> 6;
    const int b    = blockIdx.x;
    const int g    = lane >> 4;
    const int m16  = lane & 15;

    __shared__ float2 ibw[LEN];
    __shared__ float  OW[4][DIM];
    __shared__ float  Zw[4];

    // stage idx + bias; each wave writes & reads only its own 64-entry segment
    // (wave-ordered LDS -> no block barrier needed before the loop)
    {
        const int   ij = sub_index[(size_t)b * LEN + t];
        const float mk = mask[(size_t)b * LEN + t];
        ibw[t] = make_float2(__int_as_float(ij), (1.f - mk) * (-10000.f * LOG2E));
    }

    const float4 va = reinterpret_cast<const float4*>(vbuf + (size_t)b * DIM)[2 * m16];
    const float4 vb = reinterpret_cast<const float4*>(vbuf + (size_t)b * DIM)[2 * m16 + 1];
    const float qterm = qbuf[b];

    float Zr = 0.f;
    float O0=0.f,O1=0.f,O2=0.f,O3=0.f,O4=0.f,O5=0.f,O6=0.f,O7=0.f;

    const int jbase = wv * 64;
    uint4 pre[4];
    float bs[4];

    // preload 4 rows (iter k's row for group g is ibw[jbase + 4k + g])
    #pragma unroll
    for (int k = 0; k < 4; ++k) {
        const float2 ibp = ibw[jbase + 4 * k + g];
        pre[k] = *reinterpret_cast<const uint4*>(
            gfeat + (size_t)__float_as_int(ibp.x) * DIM + 8 * m16);
        bs[k] = ibp.y + qterm;
    }

    #pragma unroll
    for (int k = 0; k < 16; ++k) {
        const uint4 u  = pre[k & 3];
        const float bj = bs[k & 3];
        if (k < 12) {   // refill the freed slot with row k+4
            const float2 ibp = ibw[jbase + 4 * (k + 4) + g];
            pre[k & 3] = *reinterpret_cast<const uint4*>(
                gfeat + (size_t)__float_as_int(ibp.x) * DIM + 8 * m16);
            bs[k & 3] = ibp.y + qterm;
        }
        const float f0 = bl(u.x), f1 = bh(u.x), f2 = bl(u.y), f3 = bh(u.y);
        const float f4 = bl(u.z), f5 = bh(u.z), f6 = bl(u.w), f7 = bh(u.w);
        // tree-form dot (depth ~3)
        const float s01 = fmaf(f1, va.y, f0 * va.x);
        const float s23 = fmaf(f3, va.w, f2 * va.z);
        const float s45 = fmaf(f5, vb.y, f4 * vb.x);
        const float s67 = fmaf(f7, vb.w, f6 * vb.z);
        float sd = (s01 + s23) + (s45 + s67);
        sd += __shfl_xor(sd, 1);
        sd += __shfl_xor(sd, 2);
        sd += __shfl_xor(sd, 4);
        sd += __shfl_xor(sd, 8);
        const float e = exp2f(sd + bj);
        Zr += e;
        O0 = fmaf(e, f0, O0); O1 = fmaf(e, f1, O1);
        O2 = fmaf(e, f2, O2); O3 = fmaf(e, f3, O3);
        O4 = fmaf(e, f4, O4); O5 = fmaf(e, f5, O5);
        O6 = fmaf(e, f6, O6); O7 = fmaf(e, f7, O7);
    }

    // merge 4 groups within the wave
    #pragma unroll
    for (int msk = 16; msk <= 32; msk <<= 1) {
        Zr += __shfl_xor(Zr, msk);
        O0 += __shfl_xor(O0, msk); O1 += __shfl_xor(O1, msk);
        O2 += __shfl_xor(O2, msk); O3 += __shfl_xor(O3, msk);
        O4 += __shfl_xor(O4, msk); O5 += __shfl_xor(O5, msk);
        O6 += __shfl_xor(O6, msk); O7 += __shfl_xor(O7, msk);
    }
    if (lane < 16) {
        reinterpret_cast<float4*>(&OW[wv][0])[2 * m16]     = make_float4(O0, O1, O2, O3);
        reinterpret_cast<float4*>(&OW[wv][0])[2 * m16 + 1] = make_float4(O4, O5, O6, O7);
    }
    if (lane == 0) Zw[wv] = Zr;
    __syncthreads();

    if (t < DIM) {
        const float Zt = Zw[0] + Zw[1] + Zw[2] + Zw[3];
        out[(size_t)b * DIM + t] =
            (OW[0][t] + OW[1][t] + OW[2][t] + OW[3][t]) / Zt;
    }
}

// ---------------- tier B: f32 attention (no bfb workspace) ----------------
__global__ __launch_bounds__(256, 8) void attn_f32_kernel(
    const float* __restrict__ sub_feat, const float* __restrict__ mask,
    const int* __restrict__ sub_index, const float* __restrict__ vbuf,
    const float* __restrict__ qbuf, float* __restrict__ out)
{
    __shared__ AttnSmem sm;
    const int t = threadIdx.x;
    const int b = blockIdx.x;
    const int m16 = (t & 63) & 15;

    const int   ij = sub_index[(size_t)b * LEN + t];
    const float mk = mask[(size_t)b * LEN + t];
    sm.ibw[t] = make_float2(__int_as_float(ij), (1.f - mk) * (-10000.f * LOG2E));

    const float4 va = reinterpret_cast<const float4*>(vbuf + (size_t)b * DIM)[2 * m16];
    const float4 vb = reinterpret_cast<const float4*>(vbuf + (size_t)b * DIM)[2 * m16 + 1];
    const float qterm = qbuf[b];

    attn_core_f32(sm, t, b, va, vb, qterm, sub_feat, out);
}

// ---------------- tier C: fully self-contained (no workspace) ----------------
__global__ __launch_bounds__(256) void mono_kernel(
    const float* __restrict__ sub_feat, const float* __restrict__ mask,
    const int* __restrict__ sub_index,
    const float* __restrict__ Wq, const float* __restrict__ bq,
    const float* __restrict__ Wk, const float* __restrict__ bk,
    float* __restrict__ out)
{
    const int t    = threadIdx.x;
    const int lane = t & 63;
    const int b    = blockIdx.x;
    const int m16  = lane & 15;

    __shared__ AttnSmem sm;
    __shared__ float g0L[DIM];
    __shared__ float ph[2][DIM];
    __shared__ float q0L[DIM];
    __shared__ float vL[DIM];
    __shared__ float qbkL;

    {
        const int   ij = sub_index[(size_t)b * LEN + t];
        const float mk = mask[(size_t)b * LEN + t];
        sm.ibw[t] = make_float2(__int_as_float(ij), (1.f - mk) * (-10000.f * LOG2E));
    }
    if (t < 64) {
        const int r0 = sub_index[(size_t)b * LEN];
        const float2 p = reinterpret_cast<const float2*>(sub_feat + (size_t)r0 * DIM)[t];
        g0L[2 * t] = p.x; g0L[2 * t + 1] = p.y;
    }
    __syncthreads();

    const int d = t & (DIM - 1);
    const int h = t >> 7;
    {
        float a = 0.f;
        const int e0 = h * 64;
        #pragma unroll 4
        for (int e = e0; e < e0 + 64; ++e) a = fmaf(g0L[e], Wq[e * DIM + d], a);
        ph[h][d] = a;
    }
    __syncthreads();
    if (h == 0) q0L[d] = ph[0][d] + ph[1][d] + bq[d];
    __syncthreads();
    if (t < 64) {
        float p = q0L[t] * bk[t] + q0L[t + 64] * bk[t + 64];
        #pragma unroll
        for (int o = 32; o > 0; o >>= 1) p += __shfl_xor(p, o);
        if (t == 0) qbkL = p * SCALE_L2;
    }
    {
        float a = 0.f;
        const int d0 = h * 64;
        const float* wr = Wk + (size_t)d * DIM + d0;
        #pragma unroll 4
        for (int dd = 0; dd < 64; ++dd) a = fmaf(wr[dd], q0L[d0 + dd], a);
        ph[h][d] = a;
    }
    __syncthreads();
    if (h == 0) vL[d] = (ph[0][d] + ph[1][d]) * SCALE_L2;
    __syncthreads();

    const float4 va = reinterpret_cast<const float4*>(vL)[2 * m16];
    const float4 vb = reinterpret_cast<const float4*>(vL)[2 * m16 + 1];
    attn_core_f32(sm, t, b, va, vb, qbkL, sub_feat, out);
}

extern "C" void kernel_launch(void* const* d_in, const int* in_sizes, int n_in,
                              void* d_out, int out_size, void* d_ws, size_t ws_size,
                              hipStream_t stream) {
    const float* sub_feat  = (const float*)d_in[0];
    const float* mask      = (const float*)d_in[1];
    const float* Wq        = (const float*)d_in[2];
    const float* bq        = (const float*)d_in[3];
    const float* Wk        = (const float*)d_in[4];
    const float* bk        = (const float*)d_in[5];
    const int*   sub_index = (const int*)d_in[6];
    float* outp = (float*)d_out;
    float* ws   = (float*)d_ws;

    const int B  = in_sizes[6] / LEN;   // 2048
    const int SD = in_sizes[0];         // S*D = 524288
    const int n4 = SD / 4;
    const int nv = (B + 7) / 8;         // 256 vq blocks
    const int ncv = (n4 + 255) / 256;   // 512 convert blocks

    const size_t vq_floats  = (size_t)B * DIM + (size_t)B;
    const size_t need_vq    = vq_floats * sizeof(float);
    const size_t need_full  = need_vq + (size_t)SD * sizeof(ushort);

    float*  vbuf = ws;
    float*  qbuf = ws + (size_t)B * DIM;
    ushort* bfb  = reinterpret_cast<ushort*>(ws + vq_floats);

    if (ws_size >= need_full) {
        prep2_kernel<<<dim3(nv + ncv), dim3(256), 0, stream>>>(
            sub_feat, sub_index, Wq, bq, Wk, bk, vbuf, qbuf, bfb, n4, B, nv);
        attn_bf16_kernel<<<dim3(B), dim3(256), 0, stream>>>(
            bfb, mask, sub_index, vbuf, qbuf, outp);
    } else if (ws_size >= need_vq) {
        prep2_kernel<<<dim3(nv), dim3(256), 0, stream>>>(
            sub_feat, sub_index, Wq, bq, Wk, bk, vbuf, qbuf, nullptr, 0, B, nv);
        attn_f32_kernel<<<dim3(B), dim3(256), 0, stream>>>(
            sub_feat, mask, sub_index, vbuf, qbuf, outp);
    } else {
        mono_kernel<<<dim3(B), dim3(256), 0, stream>>>(
            sub_feat, mask, sub_index, Wq, bq, Wk, bk, outp);
    }
}

// Round 12
// 187.873 us; speedup vs baseline: 1.0199x; 1.0199x over previous
//
#include <hip/hip_runtime.h>

#define DIM 128
#define LEN 256
#define INV_SQRT_D 0.08838834764831845f
#define LOG2E 1.4426950408889634f
#define SCALE_L2 (INV_SQRT_D * LOG2E)

__device__ __forceinline__ float bl(unsigned u) { return __uint_as_float(u << 16); }
__device__ __forceinline__ float bh(unsigned u) { return __uint_as_float(u & 0xffff0000u); }

struct AttnSmem {
    float2 ibw[LEN];      // .x = idx bits, .y = mask bias (log2 units)
    float  OW[4][DIM];
    float  Zw[4];
};

// ---------------- f32 attention core (fallback tiers) ----------------
__device__ __forceinline__ void attn_core_f32(
    AttnSmem& sm, int t, int b,
    const float4& va, const float4& vb, float qterm,
    const float* __restrict__ sub_feat, float* __restrict__ out)
{
    const int lane = t & 63;
    const int wv   = t >> 6;
    const int g    = lane >> 4;
    const int m16  = lane & 15;

    float Zr = 0.f;
    float O0=0.f,O1=0.f,O2=0.f,O3=0.f,O4=0.f,O5=0.f,O6=0.f,O7=0.f;

    const int jbase = wv * 64;
    #pragma unroll 4
    for (int k = 0; k < 16; ++k) {
        const float2 ibp = sm.ibw[jbase + 4 * k + g];
        const int   ij = __float_as_int(ibp.x);
        const float bj = ibp.y;
        const float* rp = sub_feat + (size_t)ij * DIM + 8 * m16;
        const float4 u0 = *reinterpret_cast<const float4*>(rp);
        const float4 u1 = *reinterpret_cast<const float4*>(rp + 4);
        const float f0 = u0.x, f1 = u0.y, f2 = u0.z, f3 = u0.w;
        const float f4 = u1.x, f5 = u1.y, f6 = u1.z, f7 = u1.w;
        float sd = f0*va.x + f1*va.y + f2*va.z + f3*va.w
                 + f4*vb.x + f5*vb.y + f6*vb.z + f7*vb.w;
        sd += __shfl_xor(sd, 1);
        sd += __shfl_xor(sd, 2);
        sd += __shfl_xor(sd, 4);
        sd += __shfl_xor(sd, 8);
        const float e = exp2f(sd + qterm + bj);
        Zr += e;
        O0 = fmaf(e, f0, O0); O1 = fmaf(e, f1, O1);
        O2 = fmaf(e, f2, O2); O3 = fmaf(e, f3, O3);
        O4 = fmaf(e, f4, O4); O5 = fmaf(e, f5, O5);
        O6 = fmaf(e, f6, O6); O7 = fmaf(e, f7, O7);
    }

    #pragma unroll
    for (int msk = 16; msk <= 32; msk <<= 1) {
        Zr += __shfl_xor(Zr, msk);
        O0 += __shfl_xor(O0, msk); O1 += __shfl_xor(O1, msk);
        O2 += __shfl_xor(O2, msk); O3 += __shfl_xor(O3, msk);
        O4 += __shfl_xor(O4, msk); O5 += __shfl_xor(O5, msk);
        O6 += __shfl_xor(O6, msk); O7 += __shfl_xor(O7, msk);
    }
    if (lane < 16) {
        reinterpret_cast<float4*>(&sm.OW[wv][0])[2 * m16]     = make_float4(O0, O1, O2, O3);
        reinterpret_cast<float4*>(&sm.OW[wv][0])[2 * m16 + 1] = make_float4(O4, O5, O6, O7);
    }
    if (lane == 0) sm.Zw[wv] = Zr;
    __syncthreads();

    if (t < DIM) {
        const float Zt = sm.Zw[0] + sm.Zw[1] + sm.Zw[2] + sm.Zw[3];
        out[(size_t)b * DIM + t] =
            (sm.OW[0][t] + sm.OW[1][t] + sm.OW[2][t] + sm.OW[3][t]) / Zt;
    }
}

// ---------------- D1: vq (8 batches/block, no Mt) + bf16 convert ----------------
__global__ __launch_bounds__(256) void prep2_kernel(
    const float* __restrict__ sub_feat, const int* __restrict__ sub_index,
    const float* __restrict__ Wq, const float* __restrict__ bq,
    const float* __restrict__ Wk, const float* __restrict__ bk,
    float* __restrict__ vout, float* __restrict__ qout,
    ushort* __restrict__ bfb, int n4, int B, int nv)
{
    const int t   = threadIdx.x;
    const int bid = blockIdx.x;

    if (bid >= nv) {
        // bf16 convert (RNE)
        const int i = (bid - nv) * 256 + t;
        if (i < n4) {
            const float4 u = reinterpret_cast<const float4*>(sub_feat)[i];
            ushort4 o;
            unsigned a;
            a = __float_as_uint(u.x); o.x = (ushort)((a + 0x7fffu + ((a >> 16) & 1u)) >> 16);
            a = __float_as_uint(u.y); o.y = (ushort)((a + 0x7fffu + ((a >> 16) & 1u)) >> 16);
            a = __float_as_uint(u.z); o.z = (ushort)((a + 0x7fffu + ((a >> 16) & 1u)) >> 16);
            a = __float_as_uint(u.w); o.w = (ushort)((a + 0x7fffu + ((a >> 16) & 1u)) >> 16);
            reinterpret_cast<ushort4*>(bfb)[i] = o;
        }
        return;
    }

    const int lane = t & 63;
    const int wv   = t >> 6;
    const int b0   = bid * 8;

    __shared__ float g0[8][DIM];
    __shared__ float ph[2][8][DIM];
    __shared__ float q0[8][DIM];

    #pragma unroll
    for (int s = 0; s < 2; ++s) {
        const int bb = wv * 2 + s;
        const int b  = b0 + bb;
        if (b < B) {
            const int r0 = sub_index[(size_t)b * LEN];
            const float2 p = reinterpret_cast<const float2*>(sub_feat + (size_t)r0 * DIM)[lane];
            g0[bb][2 * lane]     = p.x;
            g0[bb][2 * lane + 1] = p.y;
        } else {
            g0[bb][2 * lane] = 0.f; g0[bb][2 * lane + 1] = 0.f;
        }
    }
    __syncthreads();

    const int d = t & (DIM - 1);
    const int h = t >> 7;

    // q0[b][d] = sum_e g0[b][e] * Wq[e][d] + bq[d]
    {
        float acc[8] = {0.f,0.f,0.f,0.f,0.f,0.f,0.f,0.f};
        const int e0 = h * 64;
        #pragma unroll 4
        for (int e = e0; e < e0 + 64; ++e) {
            const float w = Wq[e * DIM + d];
            #pragma unroll
            for (int bb = 0; bb < 8; ++bb) acc[bb] = fmaf(g0[bb][e], w, acc[bb]);
        }
        #pragma unroll
        for (int bb = 0; bb < 8; ++bb) ph[h][bb][d] = acc[bb];
    }
    __syncthreads();
    if (h == 0) {
        #pragma unroll
        for (int bb = 0; bb < 8; ++bb) q0[bb][d] = ph[0][bb][d] + ph[1][bb][d] + bq[d];
    }
    __syncthreads();

    // q0bk[b] pre-scaled
    #pragma unroll
    for (int s = 0; s < 2; ++s) {
        const int bb = wv * 2 + s;
        float p = q0[bb][lane] * bk[lane] + q0[bb][lane + 64] * bk[lane + 64];
        #pragma unroll
        for (int o = 32; o > 0; o >>= 1) p += __shfl_xor(p, o);
        if (lane == 0 && b0 + bb < B) qout[b0 + bb] = p * SCALE_L2;
    }

    // v[b][i] = Wk[i,:] . q0[b]
    {
        float acc[8] = {0.f,0.f,0.f,0.f,0.f,0.f,0.f,0.f};
        const int d0 = h * 64;
        const float* wrow = Wk + (size_t)d * DIM + d0;
        #pragma unroll 4
        for (int dd = 0; dd < 64; ++dd) {
            const float w = wrow[dd];
            #pragma unroll
            for (int bb = 0; bb < 8; ++bb) acc[bb] = fmaf(w, q0[bb][d0 + dd], acc[bb]);
        }
        #pragma unroll
        for (int bb = 0; bb < 8; ++bb) ph[h][bb][d] = acc[bb];
    }
    __syncthreads();
    if (h == 0) {
        #pragma unroll
        for (int bb = 0; bb < 8; ++bb) {
            if (b0 + bb < B)
                vout[(size_t)(b0 + bb) * DIM + d] = (ph[0][bb][d] + ph[1][bb][d]) * SCALE_L2;
        }
    }
}

// ---------------- D2: attention, depth-3 NAMED-REGISTER pipeline (rule-#20-safe) ----------------
__global__ __launch_bounds__(256, 8) void attn_bf16_kernel(
    const ushort* __restrict__ gfeat, const float* __restrict__ mask,
    const int* __restrict__ sub_index, const float* __restrict__ vbuf,
    const float* __restrict__ qbuf, float* __restrict__ out)
{
    const int t    = threadIdx.x;
    const int lane = t & 63;
    const int wv   = t >> 6;
    const int b    = blockIdx.x;
    const int g    = lane >> 4;
    const int m16  = lane & 15;

    __shared__ float2 ibw[LEN];
    __shared__ float  OW[4][DIM];
    __shared__ float  Zw[4];

    // stage idx + bias; each wave touches only its own 64-entry segment
    // (wave-ordered LDS -> no block barrier needed before the loop)
    {
        const int   ij = sub_index[(size_t)b * LEN + t];
        const float mk = mask[(size_t)b * LEN + t];
        ibw[t] = make_float2(__int_as_float(ij), (1.f - mk) * (-10000.f * LOG2E));
    }

    const float4 va = reinterpret_cast<const float4*>(vbuf + (size_t)b * DIM)[2 * m16];
    const float4 vb = reinterpret_cast<const float4*>(vbuf + (size_t)b * DIM)[2 * m16 + 1];
    const float qterm = qbuf[b];

    float Zr = 0.f;
    float O0=0.f,O1=0.f,O2=0.f,O3=0.f,O4=0.f,O5=0.f,O6=0.f,O7=0.f;

    const int jbase = wv * 64;

    // named pipeline slots — NO arrays, NO runtime indexing (rule #20)
    uint4 p0, p1, p2;
    float c0, c1, c2;

#define LOADS(P, C, J) { \
        const float2 ib_ = ibw[jbase + 4 * (J) + g]; \
        (P) = *reinterpret_cast<const uint4*>( \
            gfeat + (size_t)__float_as_int(ib_.x) * DIM + 8 * m16); \
        (C) = ib_.y + qterm; }

#define USES(P, C) { \
        const float f0 = bl((P).x), f1 = bh((P).x), f2 = bl((P).y), f3 = bh((P).y); \
        const float f4 = bl((P).z), f5 = bh((P).z), f6 = bl((P).w), f7 = bh((P).w); \
        const float s01 = fmaf(f1, va.y, f0 * va.x); \
        const float s23 = fmaf(f3, va.w, f2 * va.z); \
        const float s45 = fmaf(f5, vb.y, f4 * vb.x); \
        const float s67 = fmaf(f7, vb.w, f6 * vb.z); \
        float sd = (s01 + s23) + (s45 + s67); \
        sd += __shfl_xor(sd, 1); \
        sd += __shfl_xor(sd, 2); \
        sd += __shfl_xor(sd, 4); \
        sd += __shfl_xor(sd, 8); \
        const float e = exp2f(sd + (C)); \
        Zr += e; \
        O0 = fmaf(e, f0, O0); O1 = fmaf(e, f1, O1); \
        O2 = fmaf(e, f2, O2); O3 = fmaf(e, f3, O3); \
        O4 = fmaf(e, f4, O4); O5 = fmaf(e, f5, O5); \
        O6 = fmaf(e, f6, O6); O7 = fmaf(e, f7, O7); }

    LOADS(p0, c0, 0)
    LOADS(p1, c1, 1)
    LOADS(p2, c2, 2)

    USES(p0, c0) LOADS(p0, c0, 3)
    USES(p1, c1) LOADS(p1, c1, 4)
    USES(p2, c2) LOADS(p2, c2, 5)
    USES(p0, c0) LOADS(p0, c0, 6)
    USES(p1, c1) LOADS(p1, c1, 7)
    USES(p2, c2) LOADS(p2, c2, 8)
    USES(p0, c0) LOADS(p0, c0, 9)
    USES(p1, c1) LOADS(p1, c1, 10)
    USES(p2, c2) LOADS(p2, c2, 11)
    USES(p0, c0) LOADS(p0, c0, 12)
    USES(p1, c1) LOADS(p1, c1, 13)
    USES(p2, c2) LOADS(p2, c2, 14)
    USES(p0, c0) LOADS(p0, c0, 15)
    USES(p1, c1)
    USES(p2, c2)
    USES(p0, c0)

#undef LOADS
#undef USES

    // merge 4 groups within the wave
    #pragma unroll
    for (int msk = 16; msk <= 32; msk <<= 1) {
        Zr += __shfl_xor(Zr, msk);
        O0 += __shfl_xor(O0, msk); O1 += __shfl_xor(O1, msk);
        O2 += __shfl_xor(O2, msk); O3 += __shfl_xor(O3, msk);
        O4 += __shfl_xor(O4, msk); O5 += __shfl_xor(O5, msk);
        O6 += __shfl_xor(O6, msk); O7 += __shfl_xor(O7, msk);
    }
    if (lane < 16) {
        reinterpret_cast<float4*>(&OW[wv][0])[2 * m16]     = make_float4(O0, O1, O2, O3);
        reinterpret_cast<float4*>(&OW[wv][0])[2 * m16 + 1] = make_float4(O4, O5, O6, O7);
    }
    if (lane == 0) Zw[wv] = Zr;
    __syncthreads();

    if (t < DIM) {
        const float Zt = Zw[0] + Zw[1] + Zw[2] + Zw[3];
        out[(size_t)b * DIM + t] =
            (OW[0][t] + OW[1][t] + OW[2][t] + OW[3][t]) / Zt;
    }
}

// ---------------- tier B: f32 attention (no bfb workspace) ----------------
__global__ __launch_bounds__(256, 8) void attn_f32_kernel(
    const float* __restrict__ sub_feat, const float* __restrict__ mask,
    const int* __restrict__ sub_index, const float* __restrict__ vbuf,
    const float* __restrict__ qbuf, float* __restrict__ out)
{
    __shared__ AttnSmem sm;
    const int t = threadIdx.x;
    const int b = blockIdx.x;
    const int m16 = (t & 63) & 15;

    const int   ij = sub_index[(size_t)b * LEN + t];
    const float mk = mask[(size_t)b * LEN + t];
    sm.ibw[t] = make_float2(__int_as_float(ij), (1.f - mk) * (-10000.f * LOG2E));

    const float4 va = reinterpret_cast<const float4*>(vbuf + (size_t)b * DIM)[2 * m16];
    const float4 vb = reinterpret_cast<const float4*>(vbuf + (size_t)b * DIM)[2 * m16 + 1];
    const float qterm = qbuf[b];

    attn_core_f32(sm, t, b, va, vb, qterm, sub_feat, out);
}

// ---------------- tier C: fully self-contained (no workspace) ----------------
__global__ __launch_bounds__(256) void mono_kernel(
    const float* __restrict__ sub_feat, const float* __restrict__ mask,
    const int* __restrict__ sub_index,
    const float* __restrict__ Wq, const float* __restrict__ bq,
    const float* __restrict__ Wk, const float* __restrict__ bk,
    float* __restrict__ out)
{
    const int t    = threadIdx.x;
    const int lane = t & 63;
    const int b    = blockIdx.x;
    const int m16  = lane & 15;

    __shared__ AttnSmem sm;
    __shared__ float g0L[DIM];
    __shared__ float ph[2][DIM];
    __shared__ float q0L[DIM];
    __shared__ float vL[DIM];
    __shared__ float qbkL;

    {
        const int   ij = sub_index[(size_t)b * LEN + t];
        const float mk = mask[(size_t)b * LEN + t];
        sm.ibw[t] = make_float2(__int_as_float(ij), (1.f - mk) * (-10000.f * LOG2E));
    }
    if (t < 64) {
        const int r0 = sub_index[(size_t)b * LEN];
        const float2 p = reinterpret_cast<const float2*>(sub_feat + (size_t)r0 * DIM)[t];
        g0L[2 * t] = p.x; g0L[2 * t + 1] = p.y;
    }
    __syncthreads();

    const int d = t & (DIM - 1);
    const int h = t >> 7;
    {
        float a = 0.f;
        const int e0 = h * 64;
        #pragma unroll 4
        for (int e = e0; e < e0 + 64; ++e) a = fmaf(g0L[e], Wq[e * DIM + d], a);
        ph[h][d] = a;
    }
    __syncthreads();
    if (h == 0) q0L[d] = ph[0][d] + ph[1][d] + bq[d];
    __syncthreads();
    if (t < 64) {
        float p = q0L[t] * bk[t] + q0L[t + 64] * bk[t + 64];
        #pragma unroll
        for (int o = 32; o > 0; o >>= 1) p += __shfl_xor(p, o);
        if (t == 0) qbkL = p * SCALE_L2;
    }
    {
        float a = 0.f;
        const int d0 = h * 64;
        const float* wr = Wk + (size_t)d * DIM + d0;
        #pragma unroll 4
        for (int dd = 0; dd < 64; ++dd) a = fmaf(wr[dd], q0L[d0 + dd], a);
        ph[h][d] = a;
    }
    __syncthreads();
    if (h == 0) vL[d] = (ph[0][d] + ph[1][d]) * SCALE_L2;
    __syncthreads();

    const float4 va = reinterpret_cast<const float4*>(vL)[2 * m16];
    const float4 vb = reinterpret_cast<const float4*>(vL)[2 * m16 + 1];
    attn_core_f32(sm, t, b, va, vb, qbkL, sub_feat, out);
}

extern "C" void kernel_launch(void* const* d_in, const int* in_sizes, int n_in,
                              void* d_out, int out_size, void* d_ws, size_t ws_size,
                              hipStream_t stream) {
    const float* sub_feat  = (const float*)d_in[0];
    const float* mask      = (const float*)d_in[1];
    const float* Wq        = (const float*)d_in[2];
    const float* bq        = (const float*)d_in[3];
    const float* Wk        = (const float*)d_in[4];
    const float* bk        = (const float*)d_in[5];
    const int*   sub_index = (const int*)d_in[6];
    float* outp = (float*)d_out;
    float* ws   = (float*)d_ws;

    const int B  = in_sizes[6] / LEN;   // 2048
    const int SD = in_sizes[0];         // S*D = 524288
    const int n4 = SD / 4;
    const int nv = (B + 7) / 8;         // 256 vq blocks
    const int ncv = (n4 + 255) / 256;   // 512 convert blocks

    const size_t vq_floats  = (size_t)B * DIM + (size_t)B;
    const size_t need_vq    = vq_floats * sizeof(float);
    const size_t need_full  = need_vq + (size_t)SD * sizeof(ushort);

    float*  vbuf = ws;
    float*  qbuf = ws + (size_t)B * DIM;
    ushort* bfb  = reinterpret_cast<ushort*>(ws + vq_floats);

    if (ws_size >= need_full) {
        prep2_kernel<<<dim3(nv + ncv), dim3(256), 0, stream>>>(
            sub_feat, sub_index, Wq, bq, Wk, bk, vbuf, qbuf, bfb, n4, B, nv);
        attn_bf16_kernel<<<dim3(B), dim3(256), 0, stream>>>(
            bfb, mask, sub_index, vbuf, qbuf, outp);
    } else if (ws_size >= need_vq) {
        prep2_kernel<<<dim3(nv), dim3(256), 0, stream>>>(
            sub_feat, sub_index, Wq, bq, Wk, bk, vbuf, qbuf, nullptr, 0, B, nv);
        attn_f32_kernel<<<dim3(B), dim3(256), 0, stream>>>(
            sub_feat, mask, sub_index, vbuf, qbuf, outp);
    } else {
        mono_kernel<<<dim3(B), dim3(256), 0, stream>>>(
            sub_feat, mask, sub_index, Wq, bq, Wk, bk, outp);
    }
}

// Round 13
// 27.813 us; speedup vs baseline: 6.8895x; 6.7548x over previous
//
#include <hip/hip_runtime.h>

#define DIM 128
#define LEN 256
#define INV_SQRT_D 0.08838834764831845f
#define LOG2E 1.4426950408889634f
#define SCALE_L2 (INV_SQRT_D * LOG2E)

__device__ __forceinline__ float bl(unsigned u) { return __uint_as_float(u << 16); }
__device__ __forceinline__ float bh(unsigned u) { return __uint_as_float(u & 0xffff0000u); }

struct AttnSmem {
    float2 ibw[LEN];      // .x = idx bits, .y = mask bias (log2 units)
    float  OW[4][DIM];
    float  Zw[4];
};

// ---------------- f32 attention core (fallback tiers) ----------------
__device__ __forceinline__ void attn_core_f32(
    AttnSmem& sm, int t, int b,
    const float4& va, const float4& vb, float qterm,
    const float* __restrict__ sub_feat, float* __restrict__ out)
{
    const int lane = t & 63;
    const int wv   = t >> 6;
    const int g    = lane >> 4;
    const int m16  = lane & 15;

    float Zr = 0.f;
    float O0=0.f,O1=0.f,O2=0.f,O3=0.f,O4=0.f,O5=0.f,O6=0.f,O7=0.f;

    const int jbase = wv * 64;
    #pragma unroll 4
    for (int k = 0; k < 16; ++k) {
        const float2 ibp = sm.ibw[jbase + 4 * k + g];
        const int   ij = __float_as_int(ibp.x);
        const float bj = ibp.y;
        const float* rp = sub_feat + (size_t)ij * DIM + 8 * m16;
        const float4 u0 = *reinterpret_cast<const float4*>(rp);
        const float4 u1 = *reinterpret_cast<const float4*>(rp + 4);
        const float f0 = u0.x, f1 = u0.y, f2 = u0.z, f3 = u0.w;
        const float f4 = u1.x, f5 = u1.y, f6 = u1.z, f7 = u1.w;
        float sd = f0*va.x + f1*va.y + f2*va.z + f3*va.w
                 + f4*vb.x + f5*vb.y + f6*vb.z + f7*vb.w;
        sd += __shfl_xor(sd, 1);
        sd += __shfl_xor(sd, 2);
        sd += __shfl_xor(sd, 4);
        sd += __shfl_xor(sd, 8);
        const float e = exp2f(sd + qterm + bj);
        Zr += e;
        O0 = fmaf(e, f0, O0); O1 = fmaf(e, f1, O1);
        O2 = fmaf(e, f2, O2); O3 = fmaf(e, f3, O3);
        O4 = fmaf(e, f4, O4); O5 = fmaf(e, f5, O5);
        O6 = fmaf(e, f6, O6); O7 = fmaf(e, f7, O7);
    }

    #pragma unroll
    for (int msk = 16; msk <= 32; msk <<= 1) {
        Zr += __shfl_xor(Zr, msk);
        O0 += __shfl_xor(O0, msk); O1 += __shfl_xor(O1, msk);
        O2 += __shfl_xor(O2, msk); O3 += __shfl_xor(O3, msk);
        O4 += __shfl_xor(O4, msk); O5 += __shfl_xor(O5, msk);
        O6 += __shfl_xor(O6, msk); O7 += __shfl_xor(O7, msk);
    }
    if (lane < 16) {
        reinterpret_cast<float4*>(&sm.OW[wv][0])[2 * m16]     = make_float4(O0, O1, O2, O3);
        reinterpret_cast<float4*>(&sm.OW[wv][0])[2 * m16 + 1] = make_float4(O4, O5, O6, O7);
    }
    if (lane == 0) sm.Zw[wv] = Zr;
    __syncthreads();

    if (t < DIM) {
        const float Zt = sm.Zw[0] + sm.Zw[1] + sm.Zw[2] + sm.Zw[3];
        out[(size_t)b * DIM + t] =
            (sm.OW[0][t] + sm.OW[1][t] + sm.OW[2][t] + sm.OW[3][t]) / Zt;
    }
}

// ---------------- D1: vq (8 batches/block, no Mt) + bf16 convert ----------------
__global__ __launch_bounds__(256) void prep2_kernel(
    const float* __restrict__ sub_feat, const int* __restrict__ sub_index,
    const float* __restrict__ Wq, const float* __restrict__ bq,
    const float* __restrict__ Wk, const float* __restrict__ bk,
    float* __restrict__ vout, float* __restrict__ qout,
    ushort* __restrict__ bfb, int n4, int B, int nv)
{
    const int t   = threadIdx.x;
    const int bid = blockIdx.x;

    if (bid >= nv) {
        // bf16 convert (RNE)
        const int i = (bid - nv) * 256 + t;
        if (i < n4) {
            const float4 u = reinterpret_cast<const float4*>(sub_feat)[i];
            ushort4 o;
            unsigned a;
            a = __float_as_uint(u.x); o.x = (ushort)((a + 0x7fffu + ((a >> 16) & 1u)) >> 16);
            a = __float_as_uint(u.y); o.y = (ushort)((a + 0x7fffu + ((a >> 16) & 1u)) >> 16);
            a = __float_as_uint(u.z); o.z = (ushort)((a + 0x7fffu + ((a >> 16) & 1u)) >> 16);
            a = __float_as_uint(u.w); o.w = (ushort)((a + 0x7fffu + ((a >> 16) & 1u)) >> 16);
            reinterpret_cast<ushort4*>(bfb)[i] = o;
        }
        return;
    }

    const int lane = t & 63;
    const int wv   = t >> 6;
    const int b0   = bid * 8;

    __shared__ float g0[8][DIM];
    __shared__ float ph[2][8][DIM];
    __shared__ float q0[8][DIM];

    #pragma unroll
    for (int s = 0; s < 2; ++s) {
        const int bb = wv * 2 + s;
        const int b  = b0 + bb;
        if (b < B) {
            const int r0 = sub_index[(size_t)b * LEN];
            const float2 p = reinterpret_cast<const float2*>(sub_feat + (size_t)r0 * DIM)[lane];
            g0[bb][2 * lane]     = p.x;
            g0[bb][2 * lane + 1] = p.y;
        } else {
            g0[bb][2 * lane] = 0.f; g0[bb][2 * lane + 1] = 0.f;
        }
    }
    __syncthreads();

    const int d = t & (DIM - 1);
    const int h = t >> 7;

    // q0[b][d] = sum_e g0[b][e] * Wq[e][d] + bq[d]
    {
        float acc[8] = {0.f,0.f,0.f,0.f,0.f,0.f,0.f,0.f};
        const int e0 = h * 64;
        #pragma unroll 4
        for (int e = e0; e < e0 + 64; ++e) {
            const float w = Wq[e * DIM + d];
            #pragma unroll
            for (int bb = 0; bb < 8; ++bb) acc[bb] = fmaf(g0[bb][e], w, acc[bb]);
        }
        #pragma unroll
        for (int bb = 0; bb < 8; ++bb) ph[h][bb][d] = acc[bb];
    }
    __syncthreads();
    if (h == 0) {
        #pragma unroll
        for (int bb = 0; bb < 8; ++bb) q0[bb][d] = ph[0][bb][d] + ph[1][bb][d] + bq[d];
    }
    __syncthreads();

    // q0bk[b] pre-scaled
    #pragma unroll
    for (int s = 0; s < 2; ++s) {
        const int bb = wv * 2 + s;
        float p = q0[bb][lane] * bk[lane] + q0[bb][lane + 64] * bk[lane + 64];
        #pragma unroll
        for (int o = 32; o > 0; o >>= 1) p += __shfl_xor(p, o);
        if (lane == 0 && b0 + bb < B) qout[b0 + bb] = p * SCALE_L2;
    }

    // v[b][i] = Wk[i,:] . q0[b]
    {
        float acc[8] = {0.f,0.f,0.f,0.f,0.f,0.f,0.f,0.f};
        const int d0 = h * 64;
        const float* wrow = Wk + (size_t)d * DIM + d0;
        #pragma unroll 4
        for (int dd = 0; dd < 64; ++dd) {
            const float w = wrow[dd];
            #pragma unroll
            for (int bb = 0; bb < 8; ++bb) acc[bb] = fmaf(w, q0[bb][d0 + dd], acc[bb]);
        }
        #pragma unroll
        for (int bb = 0; bb < 8; ++bb) ph[h][bb][d] = acc[bb];
    }
    __syncthreads();
    if (h == 0) {
        #pragma unroll
        for (int bb = 0; bb < 8; ++bb) {
            if (b0 + bb < B)
                vout[(size_t)(b0 + bb) * DIM + d] = (ph[0][bb][d] + ph[1][bb][d]) * SCALE_L2;
        }
    }
}

// ---------------- D2: attention, 1 block = 1 batch (R9 proven: rolled loop, unroll-4) ----------------
__global__ __launch_bounds__(256, 8) void attn_bf16_kernel(
    const ushort* __restrict__ gfeat, const float* __restrict__ mask,
    const int* __restrict__ sub_index, const float* __restrict__ vbuf,
    const float* __restrict__ qbuf, float* __restrict__ out)
{
    const int t    = threadIdx.x;
    const int lane = t & 63;
    const int wv   = t >> 6;
    const int b    = blockIdx.x;
    const int g    = lane >> 4;
    const int m16  = lane & 15;

    __shared__ float2 ibw[LEN];
    __shared__ float  OW[4][DIM];
    __shared__ float  Zw[4];

    // stage idx + bias; each wave touches only its own 64-entry segment
    // (wave-ordered LDS -> no block barrier needed before the loop)
    {
        const int   ij = sub_index[(size_t)b * LEN + t];
        const float mk = mask[(size_t)b * LEN + t];
        ibw[t] = make_float2(__int_as_float(ij), (1.f - mk) * (-10000.f * LOG2E));
    }

    const float4 va = reinterpret_cast<const float4*>(vbuf + (size_t)b * DIM)[2 * m16];
    const float4 vb = reinterpret_cast<const float4*>(vbuf + (size_t)b * DIM)[2 * m16 + 1];
    const float qterm = qbuf[b];

    float Zr = 0.f;
    float O0=0.f,O1=0.f,O2=0.f,O3=0.f,O4=0.f,O5=0.f,O6=0.f,O7=0.f;

    const int jbase = wv * 64;
    #pragma unroll 4
    for (int k = 0; k < 16; ++k) {
        const float2 ibp = ibw[jbase + 4 * k + g];
        const uint4 u = *reinterpret_cast<const uint4*>(
            gfeat + (size_t)__float_as_int(ibp.x) * DIM + 8 * m16);
        const float bj = ibp.y;
        const float f0 = bl(u.x), f1 = bh(u.x), f2 = bl(u.y), f3 = bh(u.y);
        const float f4 = bl(u.z), f5 = bh(u.z), f6 = bl(u.w), f7 = bh(u.w);
        float sd = f0*va.x + f1*va.y + f2*va.z + f3*va.w
                 + f4*vb.x + f5*vb.y + f6*vb.z + f7*vb.w;
        sd += __shfl_xor(sd, 1);
        sd += __shfl_xor(sd, 2);
        sd += __shfl_xor(sd, 4);
        sd += __shfl_xor(sd, 8);
        const float e = exp2f(sd + qterm + bj);
        Zr += e;
        O0 = fmaf(e, f0, O0); O1 = fmaf(e, f1, O1);
        O2 = fmaf(e, f2, O2); O3 = fmaf(e, f3, O3);
        O4 = fmaf(e, f4, O4); O5 = fmaf(e, f5, O5);
        O6 = fmaf(e, f6, O6); O7 = fmaf(e, f7, O7);
    }

    // merge 4 groups within the wave
    #pragma unroll
    for (int msk = 16; msk <= 32; msk <<= 1) {
        Zr += __shfl_xor(Zr, msk);
        O0 += __shfl_xor(O0, msk); O1 += __shfl_xor(O1, msk);
        O2 += __shfl_xor(O2, msk); O3 += __shfl_xor(O3, msk);
        O4 += __shfl_xor(O4, msk); O5 += __shfl_xor(O5, msk);
        O6 += __shfl_xor(O6, msk); O7 += __shfl_xor(O7, msk);
    }
    if (lane < 16) {
        reinterpret_cast<float4*>(&OW[wv][0])[2 * m16]     = make_float4(O0, O1, O2, O3);
        reinterpret_cast<float4*>(&OW[wv][0])[2 * m16 + 1] = make_float4(O4, O5, O6, O7);
    }
    if (lane == 0) Zw[wv] = Zr;
    __syncthreads();

    if (t < DIM) {
        const float Zt = Zw[0] + Zw[1] + Zw[2] + Zw[3];
        out[(size_t)b * DIM + t] =
            (OW[0][t] + OW[1][t] + OW[2][t] + OW[3][t]) / Zt;
    }
}

// ---------------- tier B: f32 attention (no bfb workspace) ----------------
__global__ __launch_bounds__(256, 8) void attn_f32_kernel(
    const float* __restrict__ sub_feat, const float* __restrict__ mask,
    const int* __restrict__ sub_index, const float* __restrict__ vbuf,
    const float* __restrict__ qbuf, float* __restrict__ out)
{
    __shared__ AttnSmem sm;
    const int t = threadIdx.x;
    const int b = blockIdx.x;
    const int m16 = (t & 63) & 15;

    const int   ij = sub_index[(size_t)b * LEN + t];
    const float mk = mask[(size_t)b * LEN + t];
    sm.ibw[t] = make_float2(__int_as_float(ij), (1.f - mk) * (-10000.f * LOG2E));

    const float4 va = reinterpret_cast<const float4*>(vbuf + (size_t)b * DIM)[2 * m16];
    const float4 vb = reinterpret_cast<const float4*>(vbuf + (size_t)b * DIM)[2 * m16 + 1];
    const float qterm = qbuf[b];

    attn_core_f32(sm, t, b, va, vb, qterm, sub_feat, out);
}

// ---------------- tier C: fully self-contained (no workspace) ----------------
__global__ __launch_bounds__(256) void mono_kernel(
    const float* __restrict__ sub_feat, const float* __restrict__ mask,
    const int* __restrict__ sub_index,
    const float* __restrict__ Wq, const float* __restrict__ bq,
    const float* __restrict__ Wk, const float* __restrict__ bk,
    float* __restrict__ out)
{
    const int t    = threadIdx.x;
    const int lane = t & 63;
    const int b    = blockIdx.x;
    const int m16  = lane & 15;

    __shared__ AttnSmem sm;
    __shared__ float g0L[DIM];
    __shared__ float ph[2][DIM];
    __shared__ float q0L[DIM];
    __shared__ float vL[DIM];
    __shared__ float qbkL;

    {
        const int   ij = sub_index[(size_t)b * LEN + t];
        const float mk = mask[(size_t)b * LEN + t];
        sm.ibw[t] = make_float2(__int_as_float(ij), (1.f - mk) * (-10000.f * LOG2E));
    }
    if (t < 64) {
        const int r0 = sub_index[(size_t)b * LEN];
        const float2 p = reinterpret_cast<const float2*>(sub_feat + (size_t)r0 * DIM)[t];
        g0L[2 * t] = p.x; g0L[2 * t + 1] = p.y;
    }
    __syncthreads();

    const int d = t & (DIM - 1);
    const int h = t >> 7;
    {
        float a = 0.f;
        const int e0 = h * 64;
        #pragma unroll 4
        for (int e = e0; e < e0 + 64; ++e) a = fmaf(g0L[e], Wq[e * DIM + d], a);
        ph[h][d] = a;
    }
    __syncthreads();
    if (h == 0) q0L[d] = ph[0][d] + ph[1][d] + bq[d];
    __syncthreads();
    if (t < 64) {
        float p = q0L[t] * bk[t] + q0L[t + 64] * bk[t + 64];
        #pragma unroll
        for (int o = 32; o > 0; o >>= 1) p += __shfl_xor(p, o);
        if (t == 0) qbkL = p * SCALE_L2;
    }
    {
        float a = 0.f;
        const int d0 = h * 64;
        const float* wr = Wk + (size_t)d * DIM + d0;
        #pragma unroll 4
        for (int dd = 0; dd < 64; ++dd) a = fmaf(wr[dd], q0L[d0 + dd], a);
        ph[h][d] = a;
    }
    __syncthreads();
    if (h == 0) vL[d] = (ph[0][d] + ph[1][d]) * SCALE_L2;
    __syncthreads();

    const float4 va = reinterpret_cast<const float4*>(vL)[2 * m16];
    const float4 vb = reinterpret_cast<const float4*>(vL)[2 * m16 + 1];
    attn_core_f32(sm, t, b, va, vb, qbkL, sub_feat, out);
}

extern "C" void kernel_launch(void* const* d_in, const int* in_sizes, int n_in,
                              void* d_out, int out_size, void* d_ws, size_t ws_size,
                              hipStream_t stream) {
    const float* sub_feat  = (const float*)d_in[0];
    const float* mask      = (const float*)d_in[1];
    const float* Wq        = (const float*)d_in[2];
    const float* bq        = (const float*)d_in[3];
    const float* Wk        = (const float*)d_in[4];
    const float* bk        = (const float*)d_in[5];
    const int*   sub_index = (const int*)d_in[6];
    float* outp = (float*)d_out;
    float* ws   = (float*)d_ws;

    const int B  = in_sizes[6] / LEN;   // 2048
    const int SD = in_sizes[0];         // S*D = 524288
    const int n4 = SD / 4;
    const int nv = (B + 7) / 8;         // 256 vq blocks
    const int ncv = (n4 + 255) / 256;   // 512 convert blocks

    const size_t vq_floats  = (size_t)B * DIM + (size_t)B;
    const size_t need_vq    = vq_floats * sizeof(float);
    const size_t need_full  = need_vq + (size_t)SD * sizeof(ushort);

    float*  vbuf = ws;
    float*  qbuf = ws + (size_t)B * DIM;
    ushort* bfb  = reinterpret_cast<ushort*>(ws + vq_floats);

    if (ws_size >= need_full) {
        prep2_kernel<<<dim3(nv + ncv), dim3(256), 0, stream>>>(
            sub_feat, sub_index, Wq, bq, Wk, bk, vbuf, qbuf, bfb, n4, B, nv);
        attn_bf16_kernel<<<dim3(B), dim3(256), 0, stream>>>(
            bfb, mask, sub_index, vbuf, qbuf, outp);
    } else if (ws_size >= need_vq) {
        prep2_kernel<<<dim3(nv), dim3(256), 0, stream>>>(
            sub_feat, sub_index, Wq, bq, Wk, bk, vbuf, qbuf, nullptr, 0, B, nv);
        attn_f32_kernel<<<dim3(B), dim3(256), 0, stream>>>(
            sub_feat, mask, sub_index, vbuf, qbuf, outp);
    } else {
        mono_kernel<<<dim3(B), dim3(256), 0, stream>>>(
            sub_feat, mask, sub_index, Wq, bq, Wk, bk, outp);
    }
}